// Round 1
// baseline (552.325 us; speedup 1.0000x reference)
//
#include <hip/hip_runtime.h>

#define N_NODES 100000
#define N_EDGES 1600000
#define IN_F 256
#define OUT_F 64
#define NPAD 100096  // N_NODES rounded to multiple of 64 for aligned ws slices

__global__ __launch_bounds__(256) void deg_kernel(const int* __restrict__ src,
                                                  const int* __restrict__ dst,
                                                  int* __restrict__ deg_out,
                                                  int* __restrict__ deg_in) {
    int e = blockIdx.x * 256 + threadIdx.x;
    if (e < N_EDGES) {
        atomicAdd(&deg_out[src[e]], 1);
        atomicAdd(&deg_in[dst[e]], 1);
    }
}

__global__ __launch_bounds__(256) void norm_kernel(const int* __restrict__ deg_out,
                                                   const int* __restrict__ deg_in,
                                                   float* __restrict__ norm_out,
                                                   float* __restrict__ norm_in) {
    int i = blockIdx.x * 256 + threadIdx.x;
    if (i < N_NODES) {
        int doo = deg_out[i]; if (doo < 1) doo = 1;
        int dii = deg_in[i];  if (dii < 1) dii = 1;
        norm_out[i] = rsqrtf((float)doo);
        norm_in[i]  = rsqrtf((float)dii);
    }
}

// h[r][c] = (sum_k feat[r][k] * W[k][c]) * norm_out[r]
// 64-row tile per block, 256 threads, 4x4 register tile per thread.
__global__ __launch_bounds__(256) void gemm_kernel(const float* __restrict__ feat,
                                                   const float* __restrict__ W,
                                                   const float* __restrict__ norm_out,
                                                   float* __restrict__ h) {
    __shared__ float As[64][68];
    __shared__ float Bs[64][68];
    const int tid  = threadIdx.x;
    const int tx   = tid & 15;   // col group: cols 4*tx..4*tx+3
    const int ty   = tid >> 4;   // row group: rows ty, ty+16, ty+32, ty+48
    const int row0 = blockIdx.x * 64;
    const int lrow = tid >> 2;        // staging: row within tile
    const int lc   = (tid & 3) * 16;  // staging: col base

    float4 acc[4];
    #pragma unroll
    for (int i = 0; i < 4; ++i) acc[i] = make_float4(0.f, 0.f, 0.f, 0.f);

    for (int ks = 0; ks < IN_F; ks += 64) {
        const int gr = row0 + lrow;
        #pragma unroll
        for (int q = 0; q < 4; ++q) {
            float4 v = make_float4(0.f, 0.f, 0.f, 0.f);
            if (gr < N_NODES)
                v = *(const float4*)&feat[(long)gr * IN_F + ks + lc + 4 * q];
            *(float4*)&As[lrow][lc + 4 * q] = v;
            *(float4*)&Bs[lrow][lc + 4 * q] =
                *(const float4*)&W[(ks + lrow) * OUT_F + lc + 4 * q];
        }
        __syncthreads();
        #pragma unroll
        for (int kq = 0; kq < 16; ++kq) {
            float4 a0 = *(const float4*)&As[ty +  0][4 * kq];
            float4 a1 = *(const float4*)&As[ty + 16][4 * kq];
            float4 a2 = *(const float4*)&As[ty + 32][4 * kq];
            float4 a3 = *(const float4*)&As[ty + 48][4 * kq];
            float4 b0 = *(const float4*)&Bs[4 * kq + 0][4 * tx];
            float4 b1 = *(const float4*)&Bs[4 * kq + 1][4 * tx];
            float4 b2 = *(const float4*)&Bs[4 * kq + 2][4 * tx];
            float4 b3 = *(const float4*)&Bs[4 * kq + 3][4 * tx];
#define FMA4(ACC, S, B) \
            ACC.x = fmaf(S, B.x, ACC.x); ACC.y = fmaf(S, B.y, ACC.y); \
            ACC.z = fmaf(S, B.z, ACC.z); ACC.w = fmaf(S, B.w, ACC.w);
            FMA4(acc[0], a0.x, b0) FMA4(acc[0], a0.y, b1) FMA4(acc[0], a0.z, b2) FMA4(acc[0], a0.w, b3)
            FMA4(acc[1], a1.x, b0) FMA4(acc[1], a1.y, b1) FMA4(acc[1], a1.z, b2) FMA4(acc[1], a1.w, b3)
            FMA4(acc[2], a2.x, b0) FMA4(acc[2], a2.y, b1) FMA4(acc[2], a2.z, b2) FMA4(acc[2], a2.w, b3)
            FMA4(acc[3], a3.x, b0) FMA4(acc[3], a3.y, b1) FMA4(acc[3], a3.z, b2) FMA4(acc[3], a3.w, b3)
#undef FMA4
        }
        __syncthreads();
    }
    #pragma unroll
    for (int i = 0; i < 4; ++i) {
        int r = row0 + ty + 16 * i;
        if (r < N_NODES) {
            float s = norm_out[r];
            float4 o = acc[i];
            o.x *= s; o.y *= s; o.z *= s; o.w *= s;
            *(float4*)&h[(long)r * OUT_F + 4 * tx] = o;
        }
    }
}

// one wave per edge, lane = feature
__global__ __launch_bounds__(256) void scatter_kernel(const int* __restrict__ src,
                                                      const int* __restrict__ dst,
                                                      const float* __restrict__ h,
                                                      float* __restrict__ out) {
    long gid = (long)blockIdx.x * 256 + threadIdx.x;
    int e = (int)(gid >> 6);
    int lane = (int)(gid & 63);
    if (e < N_EDGES) {
        int s = src[e], d = dst[e];
        atomicAdd(&out[(long)d * OUT_F + lane], h[(long)s * OUT_F + lane]);
    }
}

__global__ __launch_bounds__(256) void final_kernel(float* __restrict__ out,
                                                    const float* __restrict__ norm_in,
                                                    const float* __restrict__ bias) {
    int idx = blockIdx.x * 256 + threadIdx.x;  // one float4 each
    int r = idx >> 4;
    int c = (idx & 15) * 4;
    if (r < N_NODES) {
        float s = norm_in[r];
        float4 v = *(float4*)&out[(long)r * OUT_F + c];
        float4 bb = *(const float4*)&bias[c];
        v.x = fmaxf(fmaf(v.x, s, bb.x), 0.f);
        v.y = fmaxf(fmaf(v.y, s, bb.y), 0.f);
        v.z = fmaxf(fmaf(v.z, s, bb.z), 0.f);
        v.w = fmaxf(fmaf(v.w, s, bb.w), 0.f);
        *(float4*)&out[(long)r * OUT_F + c] = v;
    }
}

extern "C" void kernel_launch(void* const* d_in, const int* in_sizes, int n_in,
                              void* d_out, int out_size, void* d_ws, size_t ws_size,
                              hipStream_t stream) {
    const float* feat = (const float*)d_in[0];
    const float* W    = (const float*)d_in[1];
    const float* bias = (const float*)d_in[2];
    const int*   src  = (const int*)d_in[3];
    const int*   dst  = (const int*)d_in[4];
    float* out = (float*)d_out;

    char* w = (char*)d_ws;
    int*   deg_out  = (int*)(w);
    int*   deg_in   = (int*)(w + (size_t)NPAD * 4);
    float* norm_out = (float*)(w + (size_t)NPAD * 8);
    float* norm_in  = (float*)(w + (size_t)NPAD * 12);
    float* h        = (float*)(w + (size_t)NPAD * 16);

    hipMemsetAsync(w, 0, (size_t)NPAD * 8, stream);                       // deg arrays
    hipMemsetAsync(out, 0, (size_t)N_NODES * OUT_F * sizeof(float), stream);

    deg_kernel<<<(N_EDGES + 255) / 256, 256, 0, stream>>>(src, dst, deg_out, deg_in);
    norm_kernel<<<(N_NODES + 255) / 256, 256, 0, stream>>>(deg_out, deg_in, norm_out, norm_in);
    gemm_kernel<<<(N_NODES + 63) / 64, 256, 0, stream>>>(feat, W, norm_out, h);
    scatter_kernel<<<(int)(((long)N_EDGES * 64) / 256), 256, 0, stream>>>(src, dst, h, out);
    final_kernel<<<(N_NODES * 16 + 255) / 256, 256, 0, stream>>>(out, norm_in, bias);
}

// Round 2
// 387.945 us; speedup vs baseline: 1.4237x; 1.4237x over previous
//
#include <hip/hip_runtime.h>

#define N_NODES 100000
#define N_EDGES 1600000
#define IN_F 256
#define OUT_F 64
#define NPAD 100096           // = 391 * 256, multiple of 256
#define SCAN_BLOCKS 391

__global__ __launch_bounds__(256) void deg_kernel(const int* __restrict__ src,
                                                  const int* __restrict__ dst,
                                                  int* __restrict__ deg_out,
                                                  int* __restrict__ deg_in) {
    int e = blockIdx.x * 256 + threadIdx.x;
    if (e < N_EDGES) {
        atomicAdd(&deg_out[src[e]], 1);
        atomicAdd(&deg_in[dst[e]], 1);
    }
}

__global__ __launch_bounds__(256) void norm_kernel(const int* __restrict__ deg_out,
                                                   float* __restrict__ norm_out) {
    int i = blockIdx.x * 256 + threadIdx.x;
    if (i < N_NODES) {
        int d = deg_out[i]; if (d < 1) d = 1;
        norm_out[i] = rsqrtf((float)d);
    }
}

// --- 3-kernel exclusive scan of deg_in[NPAD] -> row_ptr[NPAD] ---
__global__ __launch_bounds__(256) void scan1_kernel(const int* __restrict__ deg_in,
                                                    int* __restrict__ row_ptr,
                                                    int* __restrict__ block_sums) {
    __shared__ int sm[256];
    int i = blockIdx.x * 256 + threadIdx.x;
    int v = deg_in[i];
    sm[threadIdx.x] = v;
    __syncthreads();
    int x = v;
    #pragma unroll
    for (int off = 1; off < 256; off <<= 1) {
        int t = 0;
        if ((int)threadIdx.x >= off) t = sm[threadIdx.x - off];
        __syncthreads();
        x += t;
        sm[threadIdx.x] = x;
        __syncthreads();
    }
    row_ptr[i] = x - v;  // exclusive
    if (threadIdx.x == 255) block_sums[blockIdx.x] = x;
}

__global__ __launch_bounds__(512) void scan2_kernel(int* __restrict__ block_sums) {
    __shared__ int sm[512];
    int i = threadIdx.x;
    int v = (i < SCAN_BLOCKS) ? block_sums[i] : 0;
    sm[i] = v;
    __syncthreads();
    int x = v;
    #pragma unroll
    for (int off = 1; off < 512; off <<= 1) {
        int t = 0;
        if (i >= off) t = sm[i - off];
        __syncthreads();
        x += t;
        sm[i] = x;
        __syncthreads();
    }
    if (i < SCAN_BLOCKS) block_sums[i] = x - v;  // exclusive
}

__global__ __launch_bounds__(256) void scan3_kernel(int* __restrict__ row_ptr,
                                                    const int* __restrict__ block_sums,
                                                    int* __restrict__ cursor) {
    int i = blockIdx.x * 256 + threadIdx.x;
    int r = row_ptr[i] + block_sums[blockIdx.x];
    row_ptr[i] = r;
    cursor[i] = r;
}

__global__ __launch_bounds__(256) void fill_kernel(const int* __restrict__ src,
                                                   const int* __restrict__ dst,
                                                   int* __restrict__ cursor,
                                                   int* __restrict__ edge_src) {
    int e = blockIdx.x * 256 + threadIdx.x;
    if (e < N_EDGES) {
        int pos = atomicAdd(&cursor[dst[e]], 1);
        edge_src[pos] = src[e];
    }
}

// h[r][c] = (sum_k feat[r][k] * W[k][c]) * norm_out[r]
__global__ __launch_bounds__(256) void gemm_kernel(const float* __restrict__ feat,
                                                   const float* __restrict__ W,
                                                   const float* __restrict__ norm_out,
                                                   float* __restrict__ h) {
    __shared__ float As[64][68];
    __shared__ float Bs[64][68];
    const int tid  = threadIdx.x;
    const int tx   = tid & 15;
    const int ty   = tid >> 4;
    const int row0 = blockIdx.x * 64;
    const int lrow = tid >> 2;
    const int lc   = (tid & 3) * 16;

    float4 acc[4];
    #pragma unroll
    for (int i = 0; i < 4; ++i) acc[i] = make_float4(0.f, 0.f, 0.f, 0.f);

    for (int ks = 0; ks < IN_F; ks += 64) {
        const int gr = row0 + lrow;
        #pragma unroll
        for (int q = 0; q < 4; ++q) {
            float4 v = make_float4(0.f, 0.f, 0.f, 0.f);
            if (gr < N_NODES)
                v = *(const float4*)&feat[(long)gr * IN_F + ks + lc + 4 * q];
            *(float4*)&As[lrow][lc + 4 * q] = v;
            *(float4*)&Bs[lrow][lc + 4 * q] =
                *(const float4*)&W[(ks + lrow) * OUT_F + lc + 4 * q];
        }
        __syncthreads();
        #pragma unroll
        for (int kq = 0; kq < 16; ++kq) {
            float4 a0 = *(const float4*)&As[ty +  0][4 * kq];
            float4 a1 = *(const float4*)&As[ty + 16][4 * kq];
            float4 a2 = *(const float4*)&As[ty + 32][4 * kq];
            float4 a3 = *(const float4*)&As[ty + 48][4 * kq];
            float4 b0 = *(const float4*)&Bs[4 * kq + 0][4 * tx];
            float4 b1 = *(const float4*)&Bs[4 * kq + 1][4 * tx];
            float4 b2 = *(const float4*)&Bs[4 * kq + 2][4 * tx];
            float4 b3 = *(const float4*)&Bs[4 * kq + 3][4 * tx];
#define FMA4(ACC, S, B) \
            ACC.x = fmaf(S, B.x, ACC.x); ACC.y = fmaf(S, B.y, ACC.y); \
            ACC.z = fmaf(S, B.z, ACC.z); ACC.w = fmaf(S, B.w, ACC.w);
            FMA4(acc[0], a0.x, b0) FMA4(acc[0], a0.y, b1) FMA4(acc[0], a0.z, b2) FMA4(acc[0], a0.w, b3)
            FMA4(acc[1], a1.x, b0) FMA4(acc[1], a1.y, b1) FMA4(acc[1], a1.z, b2) FMA4(acc[1], a1.w, b3)
            FMA4(acc[2], a2.x, b0) FMA4(acc[2], a2.y, b1) FMA4(acc[2], a2.z, b2) FMA4(acc[2], a2.w, b3)
            FMA4(acc[3], a3.x, b0) FMA4(acc[3], a3.y, b1) FMA4(acc[3], a3.z, b2) FMA4(acc[3], a3.w, b3)
#undef FMA4
        }
        __syncthreads();
    }
    #pragma unroll
    for (int i = 0; i < 4; ++i) {
        int r = row0 + ty + 16 * i;
        if (r < N_NODES) {
            float s = norm_out[r];
            float4 o = acc[i];
            o.x *= s; o.y *= s; o.z *= s; o.w *= s;
            *(float4*)&h[(long)r * OUT_F + 4 * tx] = o;
        }
    }
}

// one wave per destination node; lane = feature. Fused norm_in + bias + relu.
__global__ __launch_bounds__(256) void aggregate_kernel(const int* __restrict__ row_ptr,
                                                        const int* __restrict__ deg_in,
                                                        const int* __restrict__ edge_src,
                                                        const float* __restrict__ h,
                                                        const float* __restrict__ bias,
                                                        float* __restrict__ out) {
    int wid  = (blockIdx.x * 256 + threadIdx.x) >> 6;
    int lane = threadIdx.x & 63;
    if (wid >= N_NODES) return;
    int deg   = deg_in[wid];
    int start = row_ptr[wid];

    float a0 = 0.f, a1 = 0.f, a2 = 0.f, a3 = 0.f;
    int j = 0;
    for (; j + 4 <= deg; j += 4) {
        int s0 = edge_src[start + j + 0];
        int s1 = edge_src[start + j + 1];
        int s2 = edge_src[start + j + 2];
        int s3 = edge_src[start + j + 3];
        a0 += h[(long)s0 * OUT_F + lane];
        a1 += h[(long)s1 * OUT_F + lane];
        a2 += h[(long)s2 * OUT_F + lane];
        a3 += h[(long)s3 * OUT_F + lane];
    }
    for (; j < deg; ++j)
        a0 += h[(long)edge_src[start + j] * OUT_F + lane];

    int dc = deg < 1 ? 1 : deg;
    float norm = rsqrtf((float)dc);
    float r = (a0 + a1 + a2 + a3) * norm + bias[lane];
    out[(long)wid * OUT_F + lane] = fmaxf(r, 0.f);
}

extern "C" void kernel_launch(void* const* d_in, const int* in_sizes, int n_in,
                              void* d_out, int out_size, void* d_ws, size_t ws_size,
                              hipStream_t stream) {
    const float* feat = (const float*)d_in[0];
    const float* W    = (const float*)d_in[1];
    const float* bias = (const float*)d_in[2];
    const int*   src  = (const int*)d_in[3];
    const int*   dst  = (const int*)d_in[4];
    float* out = (float*)d_out;

    char* w = (char*)d_ws;
    int*   deg_out    = (int*)(w);
    int*   deg_in     = (int*)(w + (size_t)NPAD * 4);
    int*   row_ptr    = (int*)(w + (size_t)NPAD * 8);
    int*   cursor     = (int*)(w + (size_t)NPAD * 12);
    float* norm_out   = (float*)(w + (size_t)NPAD * 16);
    int*   block_sums = (int*)(w + (size_t)NPAD * 20);
    int*   edge_src   = (int*)(w + (size_t)NPAD * 20 + 2048);
    float* h          = (float*)(w + (size_t)NPAD * 20 + 2048 + (size_t)N_EDGES * 4);

    // zero degree arrays (atomically incremented)
    hipMemsetAsync(w, 0, (size_t)NPAD * 8, stream);

    deg_kernel<<<(N_EDGES + 255) / 256, 256, 0, stream>>>(src, dst, deg_out, deg_in);
    norm_kernel<<<(N_NODES + 255) / 256, 256, 0, stream>>>(deg_out, norm_out);
    scan1_kernel<<<SCAN_BLOCKS, 256, 0, stream>>>(deg_in, row_ptr, block_sums);
    scan2_kernel<<<1, 512, 0, stream>>>(block_sums);
    scan3_kernel<<<SCAN_BLOCKS, 256, 0, stream>>>(row_ptr, block_sums, cursor);
    fill_kernel<<<(N_EDGES + 255) / 256, 256, 0, stream>>>(src, dst, cursor, edge_src);
    gemm_kernel<<<(N_NODES + 63) / 64, 256, 0, stream>>>(feat, W, norm_out, h);
    aggregate_kernel<<<(N_NODES * 64 + 255) / 256, 256, 0, stream>>>(
        row_ptr, deg_in, edge_src, h, bias, out);
}